// Round 4
// baseline (1183.159 us; speedup 1.0000x reference)
//
#include <hip/hip_runtime.h>

// out = relu(x @ W1) @ W2
// x: [N,155] fp32, W1: [155,128] fp32, W2: [128,3] fp32, out: [N,3] fp32.
// v6: producer/consumer wave specialization with double-buffered x tiles.
//     1024 threads: waves 8-15 stage (global f4 -> bf16 -> ds_write xs[p]),
//     waves 0-7 compute (MFMA + epilogue from xs[p^1]). 128-row tiles,
//     ONE lds_barrier (no vmcnt drain) per phase. DS write / DS read /
//     epilogue-shuffle / HBM-load traffic all flow every phase instead of
//     alternating in block-wide bursts. Epilogue xor1/xor2 via DPP quad_perm
//     (VALU) instead of ds_swizzle: halves epilogue DS ops.

#define N_TOTAL 1048576
#define IN_DIM 155
#define HIDDEN 128
#define BLOCK_THREADS 1024
#define TILE_ROWS 128
#define NTILES 32
#define ROWS_PER_BLOCK (TILE_ROWS * NTILES)  // 4096
#define XK 168                                // LDS k-stride (bf16): 336B rows, 16B aligned, 2-way-free banks
#define TILE_ELEMS (TILE_ROWS * IN_DIM)       // 19840 floats
#define TILE_F4 (TILE_ELEMS / 4)              // 4960 float4s (exactly 128 rows: no cross-tile wrap)
#define F4_PER_STAGER 10                      // ceil(4960 / 512)

typedef __attribute__((ext_vector_type(4))) float fvec4;
typedef __attribute__((ext_vector_type(8))) short short8;   // 8 bf16 MFMA A/B frag
typedef __attribute__((ext_vector_type(4))) float floatx4;  // MFMA C/D frag

static __device__ __forceinline__ unsigned short f2bf(float f) {
  // round-to-nearest-even fp32 -> bf16 (inputs are finite normals)
  unsigned int u = __builtin_bit_cast(unsigned int, f);
  u += 0x7fffu + ((u >> 16) & 1u);
  return (unsigned short)(u >> 16);
}

// LDS-visibility barrier WITHOUT vmcnt drain: prefetch loads stay in flight.
static __device__ __forceinline__ void lds_barrier() {
  __builtin_amdgcn_sched_barrier(0);
  asm volatile("s_waitcnt lgkmcnt(0)" ::: "memory");
  __builtin_amdgcn_s_barrier();
  __builtin_amdgcn_sched_barrier(0);
}

// butterfly-add via DPP quad_perm (VALU pipe, no DS op)
static __device__ __forceinline__ float dpp_add_xor1(float v) {
  const int m = __builtin_amdgcn_update_dpp(
      0, __builtin_bit_cast(int, v), 0xB1 /*quad_perm(1,0,3,2)*/, 0xf, 0xf, true);
  return v + __builtin_bit_cast(float, m);
}
static __device__ __forceinline__ float dpp_add_xor2(float v) {
  const int m = __builtin_amdgcn_update_dpp(
      0, __builtin_bit_cast(int, v), 0x4E /*quad_perm(2,3,0,1)*/, 0xf, 0xf, true);
  return v + __builtin_bit_cast(float, m);
}

__global__ __launch_bounds__(1024, 4) void fused_mlp_kernel(
    const float* __restrict__ x, const float* __restrict__ W1,
    const float* __restrict__ W2, float* __restrict__ out) {
  __shared__ __align__(16) unsigned short w1s[HIDDEN * XK];       // 43008 B
  __shared__ __align__(16) unsigned short xs[2][TILE_ROWS * XK];  // 2 x 43008 B
  __shared__ __align__(16) float w2s[HIDDEN * 3];                 // 1536 B

  const int tid = threadIdx.x;
  const int ln = tid & 15;
  const int quad = (tid >> 4) & 3;  // 16-lane group within the wave
  const int wave = tid >> 6;
  const int l = tid & 63;
  const bool stager = (wave >= 8);

  // ---- stage W1^T as bf16 into LDS (all 1024 threads) ----
  for (int idx = tid; idx < IN_DIM * HIDDEN; idx += BLOCK_THREADS) {
    const int k = idx >> 7;
    const int n = idx & 127;
    w1s[n * XK + k] = f2bf(W1[idx]);
  }
  for (int idx = tid; idx < HIDDEN * 16; idx += BLOCK_THREADS) {  // zero k-pad 155..167
    const int n = idx >> 4;
    const int k = 152 + (idx & 15);
    if (k >= IN_DIM) w1s[n * XK + k] = 0;
  }
  // zero xs k-pad cols 155..167 in both buffers (never touched by staging)
  for (int idx = tid; idx < 2 * TILE_ROWS * 13; idx += BLOCK_THREADS) {
    const int b = idx >= TILE_ROWS * 13;
    const int i2 = idx - b * TILE_ROWS * 13;
    const int r = i2 / 13;
    const int c = IN_DIM + (i2 - r * 13);
    xs[b][r * XK + c] = 0;
  }
  for (int idx = tid; idx < HIDDEN * 3; idx += BLOCK_THREADS) w2s[idx] = W2[idx];
  __syncthreads();  // init barrier: full drain fine (nothing in flight)

  const size_t block_e0 = (size_t)blockIdx.x * ROWS_PER_BLOCK * IN_DIM;
  const size_t brow0 = (size_t)blockIdx.x * ROWS_PER_BLOCK;

  // epilogue routing: dst lane l (<48) pulls from src lane 16*(l/12) + (l%12)
  const int srcaddr = ((l / 12) * 16 + (l % 12)) << 2;

  // ---- stagers: prefetch tile 0 (flat coalesced float4, 16B aligned) ----
  fvec4 pre[F4_PER_STAGER];
  const int st = tid - 512;  // stager index 0..511 (only valid when stager)
  if (stager) {
    const fvec4* src = reinterpret_cast<const fvec4*>(x + block_e0);
#pragma unroll
    for (int i = 0; i < F4_PER_STAGER; ++i) {
      const int f = st + i * 512;
      if (f < TILE_F4) pre[i] = src[f];
    }
  }

  // ---- pipeline: phase t: stagers convert tile t -> xs[t&1], issue loads of
  //      tile t+1; computers crunch tile t-1 from xs[(t-1)&1]. One barrier. ----
  for (int t = 0; t <= NTILES; ++t) {
    const int p = t & 1;
    if (stager) {
      if (t < NTILES) {
        unsigned short* xb = xs[p];
        const fvec4* nsrc = reinterpret_cast<const fvec4*>(
            x + block_e0 + (size_t)(t + 1) * TILE_ELEMS);
        const bool more = (t + 1 < NTILES);
#pragma unroll
        for (int i = 0; i < F4_PER_STAGER; ++i) {
          const int f = st + i * 512;
          if (f < TILE_F4) {
            const fvec4 v = pre[i];
            const int e0 = f * 4;
            const int r = e0 / IN_DIM;
            const int c = e0 - r * IN_DIM;
#pragma unroll
            for (int j = 0; j < 4; ++j) {
              const int cc = c + j;
              const int wrap = (cc >= IN_DIM);
              xb[(r + wrap) * XK + (cc - wrap * IN_DIM)] = f2bf(v[j]);
            }
            if (more) pre[i] = nsrc[f];  // in flight across the barrier;
                                         // consumed next phase (full-phase cover)
          }
        }
      }
    } else if (t >= 1) {
      const unsigned short* xb = xs[p ^ 1];

      // ---- layer 1: 16 rows per wave, B-frags from LDS ----
      floatx4 acc[8];
#pragma unroll
      for (int c8 = 0; c8 < 8; ++c8) acc[c8] = (floatx4)0.f;
      const int rbase = wave * 16;
#pragma unroll
      for (int s = 0; s < 5; ++s) {
        const int kb = s * 32 + quad * 8;
        const short8 a = *reinterpret_cast<const short8*>(&xb[(rbase + ln) * XK + kb]);
#pragma unroll
        for (int t8 = 0; t8 < 8; ++t8) {
          const short8 b =
              *reinterpret_cast<const short8*>(&w1s[(t8 * 16 + ln) * XK + kb]);
          acc[t8] = __builtin_amdgcn_mfma_f32_16x16x32_bf16(a, b, acc[t8], 0, 0, 0);
        }
      }

      // ---- layer 2: relu + W2, reduce across 16-lane group ----
      float part[4][3];
#pragma unroll
      for (int r = 0; r < 4; ++r)
#pragma unroll
        for (int c = 0; c < 3; ++c) part[r][c] = 0.f;
#pragma unroll
      for (int t8 = 0; t8 < 8; ++t8) {
        const float wa = w2s[(t8 * 16 + ln) * 3 + 0];
        const float wb = w2s[(t8 * 16 + ln) * 3 + 1];
        const float wc = w2s[(t8 * 16 + ln) * 3 + 2];
#pragma unroll
        for (int r = 0; r < 4; ++r) {
          const float hv = fmaxf(acc[t8][r], 0.f);
          part[r][0] = fmaf(hv, wa, part[r][0]);
          part[r][1] = fmaf(hv, wb, part[r][1]);
          part[r][2] = fmaf(hv, wc, part[r][2]);
        }
      }
      // xor1/xor2 on VALU (DPP), xor4/xor8 on DS (swizzle)
#pragma unroll
      for (int r = 0; r < 4; ++r)
#pragma unroll
        for (int c = 0; c < 3; ++c) {
          float v = part[r][c];
          v = dpp_add_xor1(v);
          v = dpp_add_xor2(v);
          v += __shfl_xor(v, 4, 16);
          v += __shfl_xor(v, 8, 16);
          part[r][c] = v;
        }

      // ---- single coalesced 192B store per wave ----
      float v = part[0][0];
      v = (ln == 1) ? part[0][1] : v;
      v = (ln == 2) ? part[0][2] : v;
      v = (ln == 3) ? part[1][0] : v;
      v = (ln == 4) ? part[1][1] : v;
      v = (ln == 5) ? part[1][2] : v;
      v = (ln == 6) ? part[2][0] : v;
      v = (ln == 7) ? part[2][1] : v;
      v = (ln == 8) ? part[2][2] : v;
      v = (ln == 9) ? part[3][0] : v;
      v = (ln == 10) ? part[3][1] : v;
      v = (ln == 11) ? part[3][2] : v;
      const int vo = __builtin_amdgcn_ds_bpermute(srcaddr, __builtin_bit_cast(int, v));
      const size_t row0 = brow0 + (size_t)(t - 1) * TILE_ROWS + wave * 16;
      if (l < 48) out[row0 * 3 + l] = __builtin_bit_cast(float, vo);
    }

    lds_barrier();  // phase boundary: xs[p] now visible; xs[p^1] free to overwrite
  }
}

extern "C" void kernel_launch(void* const* d_in, const int* in_sizes, int n_in,
                              void* d_out, int out_size, void* d_ws, size_t ws_size,
                              hipStream_t stream) {
  const float* x = (const float*)d_in[0];
  const float* W1 = (const float*)d_in[1];
  const float* W2 = (const float*)d_in[2];
  float* out = (float*)d_out;
  fused_mlp_kernel<<<dim3(N_TOTAL / ROWS_PER_BLOCK), dim3(BLOCK_THREADS), 0, stream>>>(
      x, W1, W2, out);
}

// Round 5
// 980.655 us; speedup vs baseline: 1.2065x; 1.2065x over previous
//
#include <hip/hip_runtime.h>

// out = relu(x @ W1) @ W2
// x: [N,155] fp32, W1: [155,128] fp32, W2: [128,3] fp32, out: [N,3] fp32.
// v7: v4 skeleton (coalesced f4 staging -> bf16 LDS -> MFMA, 2-barrier loop,
//     no specialization) with three DS-volume cuts so the tile period drops
//     below the per-tile HBM delivery time (-> HBM stays busy every cycle):
//     1) 512 thr / 8 waves, 32 rows per wave: two 16-row sub-tiles share each
//        W1 B-frag read (B ds_read_b128 halved; VGPR cap 256 -> no spill).
//     2) 16-lane reduce entirely on DPP row_ror (VALU) -- epilogue DS ops
//        drop from 48/wave to 1 bpermute.
//     3) W2 in registers (w2r[8][3]) instead of LDS.

#define N_TOTAL 1048576
#define IN_DIM 155
#define HIDDEN 128
#define BLOCK_THREADS 512
#define TILE_ROWS 256
#define NTILES 16
#define ROWS_PER_BLOCK (TILE_ROWS * NTILES)  // 4096
#define XK 168                                // LDS k-stride (bf16): 336B rows, 16B aligned
#define TILE_ELEMS (TILE_ROWS * IN_DIM)       // 39680 floats
#define TILE_F4 (TILE_ELEMS / 4)              // 9920 float4s
#define F4_PER_THREAD 20                      // ceil(9920 / 512)

typedef __attribute__((ext_vector_type(4))) float fvec4;
typedef __attribute__((ext_vector_type(8))) short short8;   // 8 bf16 MFMA A/B frag
typedef __attribute__((ext_vector_type(4))) float floatx4;  // MFMA C/D frag

static __device__ __forceinline__ unsigned short f2bf(float f) {
  // round-to-nearest-even fp32 -> bf16 (inputs are finite normals)
  unsigned int u = __builtin_bit_cast(unsigned int, f);
  u += 0x7fffu + ((u >> 16) & 1u);
  return (unsigned short)(u >> 16);
}

// LDS-visibility barrier WITHOUT vmcnt drain: prefetch loads stay in flight.
static __device__ __forceinline__ void lds_barrier() {
  __builtin_amdgcn_sched_barrier(0);
  asm volatile("s_waitcnt lgkmcnt(0)" ::: "memory");
  __builtin_amdgcn_s_barrier();
  __builtin_amdgcn_sched_barrier(0);
}

// v += row_ror<N>(v): rotate within the 16-lane DPP row (VALU pipe, no DS op).
// ror 8,4,2,1 chain = full 16-lane sum in every lane.
template <int CTRL>
static __device__ __forceinline__ float dpp_ror_add(float v) {
  const int m = __builtin_amdgcn_update_dpp(
      0, __builtin_bit_cast(int, v), CTRL, 0xf, 0xf, true);
  return v + __builtin_bit_cast(float, m);
}

static __device__ __forceinline__ void epilogue_16rows(
    const floatx4* acc, const float w2r[8][3], int ln, int l, int srcaddr,
    float* __restrict__ out, size_t row0) {
  // acc[t8][r] = h[row0 + quad*4 + r][16*t8 + ln]
  float part[4][3];
#pragma unroll
  for (int r = 0; r < 4; ++r)
#pragma unroll
    for (int c = 0; c < 3; ++c) part[r][c] = 0.f;

#pragma unroll
  for (int t8 = 0; t8 < 8; ++t8) {
#pragma unroll
    for (int r = 0; r < 4; ++r) {
      const float hv = fmaxf(acc[t8][r], 0.f);
      part[r][0] = fmaf(hv, w2r[t8][0], part[r][0]);
      part[r][1] = fmaf(hv, w2r[t8][1], part[r][1]);
      part[r][2] = fmaf(hv, w2r[t8][2], part[r][2]);
    }
  }
  // full 16-lane reduce on DPP row_ror (12 independent 4-deep chains)
#pragma unroll
  for (int r = 0; r < 4; ++r)
#pragma unroll
    for (int c = 0; c < 3; ++c) {
      float v = part[r][c];
      v = dpp_ror_add<0x128>(v);  // ror 8
      v = dpp_ror_add<0x124>(v);  // ror 4
      v = dpp_ror_add<0x122>(v);  // ror 2
      v = dpp_ror_add<0x121>(v);  // ror 1
      part[r][c] = v;
    }

  // lane j (j<12) of each 16-lane group selects part[j/3][j%3], then dst
  // lane l pulls from lane 16*(l/12) + (l%12): one coalesced 192B store/wave.
  float v = part[0][0];
  v = (ln == 1) ? part[0][1] : v;
  v = (ln == 2) ? part[0][2] : v;
  v = (ln == 3) ? part[1][0] : v;
  v = (ln == 4) ? part[1][1] : v;
  v = (ln == 5) ? part[1][2] : v;
  v = (ln == 6) ? part[2][0] : v;
  v = (ln == 7) ? part[2][1] : v;
  v = (ln == 8) ? part[2][2] : v;
  v = (ln == 9) ? part[3][0] : v;
  v = (ln == 10) ? part[3][1] : v;
  v = (ln == 11) ? part[3][2] : v;
  const int vo = __builtin_amdgcn_ds_bpermute(srcaddr, __builtin_bit_cast(int, v));
  if (l < 48) out[row0 * 3 + l] = __builtin_bit_cast(float, vo);
}

__global__ __launch_bounds__(512, 2) void fused_mlp_kernel(
    const float* __restrict__ x, const float* __restrict__ W1,
    const float* __restrict__ W2, float* __restrict__ out) {
  __shared__ __align__(16) unsigned short w1s[HIDDEN * XK];    // 43008 B
  __shared__ __align__(16) unsigned short xs[TILE_ROWS * XK];  // 86016 B

  const int tid = threadIdx.x;
  const int ln = tid & 15;
  const int quad = (tid >> 4) & 3;  // 16-lane group within the wave
  const int wave = tid >> 6;        // 0..7
  const int l = tid & 63;

  // ---- stage W1^T as bf16 into LDS ----
  for (int idx = tid; idx < IN_DIM * HIDDEN; idx += BLOCK_THREADS) {
    const int k = idx >> 7;
    const int n = idx & 127;
    w1s[n * XK + k] = f2bf(W1[idx]);
  }
  for (int idx = tid; idx < HIDDEN * 16; idx += BLOCK_THREADS) {  // zero k-pad 155..167
    const int n = idx >> 4;
    const int k = 152 + (idx & 15);
    if (k >= IN_DIM) w1s[n * XK + k] = 0;
  }
  // zero xs k-pad cols 155..167 (never overwritten by staging)
  for (int idx = tid; idx < TILE_ROWS * 13; idx += BLOCK_THREADS) {
    const int r = idx / 13;
    const int c = IN_DIM + (idx - r * 13);
    xs[r * XK + c] = 0;
  }
  // ---- W2 into registers (L2-resident, once per block) ----
  float w2r[8][3];
#pragma unroll
  for (int t8 = 0; t8 < 8; ++t8)
#pragma unroll
    for (int c = 0; c < 3; ++c) w2r[t8][c] = W2[(t8 * 16 + ln) * 3 + c];
  __syncthreads();  // init barrier: full drain fine (nothing in flight)

  const size_t block_e0 = (size_t)blockIdx.x * ROWS_PER_BLOCK * IN_DIM;
  const size_t brow0 = (size_t)blockIdx.x * ROWS_PER_BLOCK;

  // epilogue routing: dst lane l (<48) pulls from src lane 16*(l/12) + (l%12)
  const int srcaddr = ((l / 12) * 16 + (l % 12)) << 2;

  // ---- prefetch tile 0 (flat coalesced float4, 16B aligned) ----
  fvec4 pre[F4_PER_THREAD];
  {
    const fvec4* src = reinterpret_cast<const fvec4*>(x + block_e0);
#pragma unroll
    for (int i = 0; i < F4_PER_THREAD; ++i) {
      const int f = tid + i * BLOCK_THREADS;
      if (f < TILE_F4) pre[i] = src[f];
    }
  }

  for (int t = 0; t < NTILES; ++t) {
    // ---- convert prefetched tile -> xs; re-issue each pre[i]'s next-tile
    //      load right after its last read (in flight across both barriers,
    //      full iteration of cover; the whole iter's 159KB/CU is outstanding) ----
    const bool more = (t + 1 < NTILES);
    const fvec4* nsrc = reinterpret_cast<const fvec4*>(
        x + block_e0 + (size_t)(t + 1) * TILE_ELEMS);
#pragma unroll
    for (int i = 0; i < F4_PER_THREAD; ++i) {
      const int f = tid + i * BLOCK_THREADS;
      if (f < TILE_F4) {
        const fvec4 v = pre[i];
        const int e0 = f * 4;
        const int r = e0 / IN_DIM;
        const int c = e0 - r * IN_DIM;
#pragma unroll
        for (int j = 0; j < 4; ++j) {
          const int cc = c + j;
          const int wrap = (cc >= IN_DIM);
          xs[(r + wrap) * XK + (cc - wrap * IN_DIM)] = f2bf(v[j]);
        }
        if (more) pre[i] = nsrc[f];
      }
    }
    lds_barrier();  // xs visible; vmcnt NOT drained

    // ---- layer 1: 32 rows per wave (two 16-row sub-tiles), shared B-frags ----
    floatx4 acc0[8], acc1[8];
#pragma unroll
    for (int c8 = 0; c8 < 8; ++c8) {
      acc0[c8] = (floatx4)0.f;
      acc1[c8] = (floatx4)0.f;
    }
    const int rbase = wave * 32;
#pragma unroll
    for (int s = 0; s < 5; ++s) {
      const int kb = s * 32 + quad * 8;
      const short8 a0 = *reinterpret_cast<const short8*>(&xs[(rbase + ln) * XK + kb]);
      const short8 a1 =
          *reinterpret_cast<const short8*>(&xs[(rbase + 16 + ln) * XK + kb]);
#pragma unroll
      for (int t8 = 0; t8 < 8; ++t8) {
        const short8 b =
            *reinterpret_cast<const short8*>(&w1s[(t8 * 16 + ln) * XK + kb]);
        acc0[t8] = __builtin_amdgcn_mfma_f32_16x16x32_bf16(a0, b, acc0[t8], 0, 0, 0);
        acc1[t8] = __builtin_amdgcn_mfma_f32_16x16x32_bf16(a1, b, acc1[t8], 0, 0, 0);
      }
    }

    // ---- layer 2 + store ----
    const size_t row0 = brow0 + (size_t)t * TILE_ROWS + wave * 32;
    epilogue_16rows(acc0, w2r, ln, l, srcaddr, out, row0);
    epilogue_16rows(acc1, w2r, ln, l, srcaddr, out, row0 + 16);

    lds_barrier();  // all waves done reading xs before next overwrite
  }
}

extern "C" void kernel_launch(void* const* d_in, const int* in_sizes, int n_in,
                              void* d_out, int out_size, void* d_ws, size_t ws_size,
                              hipStream_t stream) {
  const float* x = (const float*)d_in[0];
  const float* W1 = (const float*)d_in[1];
  const float* W2 = (const float*)d_in[2];
  float* out = (float*)d_out;
  fused_mlp_kernel<<<dim3(N_TOTAL / ROWS_PER_BLOCK), dim3(BLOCK_THREADS), 0, stream>>>(
      x, W1, W2, out);
}

// Round 6
// 921.329 us; speedup vs baseline: 1.2842x; 1.0644x over previous
//
#include <hip/hip_runtime.h>

// out = relu(x @ W1) @ W2
// x: [N,155] fp32, W1: [155,128] fp32, W2: [128,3] fp32, out: [N,3] fp32.
// v8: v4's exact structure (1024 thr / 16 waves / 4 per SIMD, 256-row tiles,
//     coalesced f4 staging -> bf16 LDS, plain __syncthreads pipeline) + two
//     surgical DS cuts validated in v7:
//       1) epilogue 16-lane reduce entirely on DPP row_ror (VALU pipe) --
//          removes 768 shfl DS-ops per tile (suspected bank-conflict source).
//       2) W2 in registers (24 VGPRs, loaded once) -- removes 384
//          ds_read_b32 per tile.
//     Everything else is byte-identical to v4 (the best-measured variant).

#define N_TOTAL 1048576
#define IN_DIM 155
#define HIDDEN 128
#define BLOCK_THREADS 1024
#define TILE_ROWS 256
#define NTILES 16
#define ROWS_PER_BLOCK (TILE_ROWS * NTILES)  // 4096
#define XK 168                                // LDS k-stride (bf16): 336B rows, 16B aligned
#define TILE_ELEMS (TILE_ROWS * IN_DIM)       // 39680 floats
#define TILE_F4 (TILE_ELEMS / 4)              // 9920 float4s
#define F4_PER_THREAD 10                      // ceil(9920 / 1024)

typedef __attribute__((ext_vector_type(4))) float fvec4;
typedef __attribute__((ext_vector_type(8))) short short8;   // 8 bf16 MFMA A/B frag
typedef __attribute__((ext_vector_type(4))) float floatx4;  // MFMA C/D frag

static __device__ __forceinline__ unsigned short f2bf(float f) {
  // round-to-nearest-even fp32 -> bf16 (inputs are finite normals)
  unsigned int u = __builtin_bit_cast(unsigned int, f);
  u += 0x7fffu + ((u >> 16) & 1u);
  return (unsigned short)(u >> 16);
}

// v += row_ror<N>(v): rotate within the 16-lane DPP row (VALU pipe, no DS op).
// ror 8,4,2,1 chain = full 16-lane sum in every lane. (validated in v7)
template <int CTRL>
static __device__ __forceinline__ float dpp_ror_add(float v) {
  const int m = __builtin_amdgcn_update_dpp(
      0, __builtin_bit_cast(int, v), CTRL, 0xf, 0xf, true);
  return v + __builtin_bit_cast(float, m);
}

__global__ __launch_bounds__(1024, 4) void fused_mlp_kernel(
    const float* __restrict__ x, const float* __restrict__ W1,
    const float* __restrict__ W2, float* __restrict__ out) {
  __shared__ __align__(16) unsigned short w1s[HIDDEN * XK];    // 43008 B, W1^T bf16
  __shared__ __align__(16) unsigned short xs[TILE_ROWS * XK];  // 86016 B, x tile bf16

  const int tid = threadIdx.x;
  const int ln = tid & 15;
  const int quad = (tid >> 4) & 3;  // 16-lane group within the wave
  const int wave = tid >> 6;
  const int l = tid & 63;

  // ---- stage W1^T as bf16 into LDS ----
  for (int idx = tid; idx < IN_DIM * HIDDEN; idx += BLOCK_THREADS) {
    const int k = idx >> 7;
    const int n = idx & 127;
    w1s[n * XK + k] = f2bf(W1[idx]);
  }
  for (int idx = tid; idx < HIDDEN * 16; idx += BLOCK_THREADS) {  // zero k-pad 155..167
    const int n = idx >> 4;
    const int k = 152 + (idx & 15);
    if (k >= IN_DIM) w1s[n * XK + k] = 0;
  }
  // zero xs k-pad cols 155..167 (never overwritten by staging)
  for (int idx = tid; idx < TILE_ROWS * 13; idx += BLOCK_THREADS) {
    const int r = idx / 13;
    const int c = IN_DIM + (idx - r * 13);
    xs[r * XK + c] = 0;
  }
  // ---- W2 into registers (L2-resident; once per kernel, not per tile) ----
  float w2r[8][3];
#pragma unroll
  for (int t8 = 0; t8 < 8; ++t8)
#pragma unroll
    for (int c = 0; c < 3; ++c) w2r[t8][c] = W2[(t8 * 16 + ln) * 3 + c];
  __syncthreads();

  const size_t block_e0 = (size_t)blockIdx.x * ROWS_PER_BLOCK * IN_DIM;
  const size_t brow0 = (size_t)blockIdx.x * ROWS_PER_BLOCK;

  // epilogue routing: dst lane l (<48) pulls from src lane 16*(l/12) + (l%12)
  const int srcaddr = ((l / 12) * 16 + (l % 12)) << 2;

  // ---- prefetch tile 0 (flat coalesced float4, 16B aligned) ----
  fvec4 pre[F4_PER_THREAD];
  {
    const fvec4* src = reinterpret_cast<const fvec4*>(x + block_e0);
#pragma unroll
    for (int i = 0; i < F4_PER_THREAD; ++i) {
      const int f = tid + i * BLOCK_THREADS;
      if (f < TILE_F4) pre[i] = src[f];
    }
  }

  for (int t = 0; t < NTILES; ++t) {
    // ---- convert prefetched tile -> xs (bf16, padded rows) ----
#pragma unroll
    for (int i = 0; i < F4_PER_THREAD; ++i) {
      const int f = tid + i * BLOCK_THREADS;
      if (f < TILE_F4) {
        const int e0 = f * 4;
        const int r = e0 / IN_DIM;
        const int c = e0 - r * IN_DIM;
#pragma unroll
        for (int j = 0; j < 4; ++j) {
          const int cc = c + j;
          const int wrap = (cc >= IN_DIM);
          xs[(r + wrap) * XK + (cc - wrap * IN_DIM)] = f2bf(pre[i][j]);
        }
      }
    }
    __syncthreads();

    // ---- issue next tile's loads AFTER the barrier (in flight under
    //      compute + epilogue; drained by the end-of-loop barrier) ----
    if (t + 1 < NTILES) {
      const fvec4* src = reinterpret_cast<const fvec4*>(
          x + block_e0 + (size_t)(t + 1) * TILE_ELEMS);
#pragma unroll
      for (int i = 0; i < F4_PER_THREAD; ++i) {
        const int f = tid + i * BLOCK_THREADS;
        if (f < TILE_F4) pre[i] = src[f];
      }
    }

    // ---- layer 1: 16 rows per wave, B-frags from LDS ----
    floatx4 acc[8];
#pragma unroll
    for (int c8 = 0; c8 < 8; ++c8) acc[c8] = (floatx4)0.f;
    const int rbase = wave * 16;
#pragma unroll
    for (int s = 0; s < 5; ++s) {
      const int kb = s * 32 + quad * 8;
      const short8 a = *reinterpret_cast<const short8*>(&xs[(rbase + ln) * XK + kb]);
#pragma unroll
      for (int t8 = 0; t8 < 8; ++t8) {
        const short8 b = *reinterpret_cast<const short8*>(&w1s[(t8 * 16 + ln) * XK + kb]);
        acc[t8] = __builtin_amdgcn_mfma_f32_16x16x32_bf16(a, b, acc[t8], 0, 0, 0);
      }
    }

    // ---- layer 2: relu + W2, reduce across 16-lane group ----
    // acc[t8][r] = h[row0 + quad*4 + r][16*t8 + ln]
    float part[4][3];
#pragma unroll
    for (int r = 0; r < 4; ++r)
#pragma unroll
      for (int c = 0; c < 3; ++c) part[r][c] = 0.f;
#pragma unroll
    for (int t8 = 0; t8 < 8; ++t8) {
#pragma unroll
      for (int r = 0; r < 4; ++r) {
        const float hv = fmaxf(acc[t8][r], 0.f);
        part[r][0] = fmaf(hv, w2r[t8][0], part[r][0]);
        part[r][1] = fmaf(hv, w2r[t8][1], part[r][1]);
        part[r][2] = fmaf(hv, w2r[t8][2], part[r][2]);
      }
    }
    // full 16-lane reduce on DPP row_ror (VALU pipe; no DS ops, no conflicts)
#pragma unroll
    for (int r = 0; r < 4; ++r)
#pragma unroll
      for (int c = 0; c < 3; ++c) {
        float v = part[r][c];
        v = dpp_ror_add<0x128>(v);  // ror 8
        v = dpp_ror_add<0x124>(v);  // ror 4
        v = dpp_ror_add<0x122>(v);  // ror 2
        v = dpp_ror_add<0x121>(v);  // ror 1
        part[r][c] = v;
      }

    // ---- single coalesced 192B store per wave ----
    // lane j (j<12) of each 16-lane group selects part[j/3][j%3] (cndmask
    // tree), then dst lane l pulls from lane 16*(l/12) + (l%12).
    float v = part[0][0];
    v = (ln == 1) ? part[0][1] : v;
    v = (ln == 2) ? part[0][2] : v;
    v = (ln == 3) ? part[1][0] : v;
    v = (ln == 4) ? part[1][1] : v;
    v = (ln == 5) ? part[1][2] : v;
    v = (ln == 6) ? part[2][0] : v;
    v = (ln == 7) ? part[2][1] : v;
    v = (ln == 8) ? part[2][2] : v;
    v = (ln == 9) ? part[3][0] : v;
    v = (ln == 10) ? part[3][1] : v;
    v = (ln == 11) ? part[3][2] : v;
    const int vo = __builtin_amdgcn_ds_bpermute(srcaddr, __builtin_bit_cast(int, v));
    const size_t row0 = brow0 + (size_t)t * TILE_ROWS + wave * 16;
    if (l < 48) out[row0 * 3 + l] = __builtin_bit_cast(float, vo);

    __syncthreads();  // all waves done reading xs before next overwrite
  }
}

extern "C" void kernel_launch(void* const* d_in, const int* in_sizes, int n_in,
                              void* d_out, int out_size, void* d_ws, size_t ws_size,
                              hipStream_t stream) {
  const float* x = (const float*)d_in[0];
  const float* W1 = (const float*)d_in[1];
  const float* W2 = (const float*)d_in[2];
  float* out = (float*)d_out;
  fused_mlp_kernel<<<dim3(N_TOTAL / ROWS_PER_BLOCK), dim3(BLOCK_THREADS), 0, stream>>>(
      x, W1, W2, out);
}

// Round 7
// 834.140 us; speedup vs baseline: 1.4184x; 1.1045x over previous
//
#include <hip/hip_runtime.h>

// out = relu(x @ W1) @ W2
// x: [N,155] fp32, W1: [155,128] fp32, W2: [128,3] fp32, out: [N,3] fp32.
// v9: v4 (best measured: dur 850, kernel ~213us) with EXACTLY ONE change:
//     the epilogue 16-lane shfl_xor reduce (768 ds_swizzle ops/tile, suspect
//     bank-conflict source) is replaced by a DPP row_ror 8/4/2/1 add chain
//     (VALU pipe, zero DS ops). W2 stays in LDS (v8 showed moving it to
//     registers risks spill at the 128-VGPR cap of launch_bounds(1024,4)).
//     Everything else is byte-identical to v4.

#define N_TOTAL 1048576
#define IN_DIM 155
#define HIDDEN 128
#define BLOCK_THREADS 1024
#define TILE_ROWS 256
#define NTILES 16
#define ROWS_PER_BLOCK (TILE_ROWS * NTILES)  // 4096
#define XK 168                                // LDS k-stride (bf16): 336B rows, 16B aligned
#define TILE_ELEMS (TILE_ROWS * IN_DIM)       // 39680 floats
#define TILE_F4 (TILE_ELEMS / 4)              // 9920 float4s
#define F4_PER_THREAD 10                      // ceil(9920 / 1024)

typedef __attribute__((ext_vector_type(4))) float fvec4;
typedef __attribute__((ext_vector_type(8))) short short8;   // 8 bf16 MFMA A/B frag
typedef __attribute__((ext_vector_type(4))) float floatx4;  // MFMA C/D frag

static __device__ __forceinline__ unsigned short f2bf(float f) {
  // round-to-nearest-even fp32 -> bf16 (inputs are finite normals)
  unsigned int u = __builtin_bit_cast(unsigned int, f);
  u += 0x7fffu + ((u >> 16) & 1u);
  return (unsigned short)(u >> 16);
}

// v += row_ror<N>(v): rotate within the 16-lane DPP row (VALU pipe, no DS op).
// ror 8,4,2,1 chain = full 16-lane sum in every lane. (correctness validated
// in v7/v8: absmax identical to the shfl_xor version)
template <int CTRL>
static __device__ __forceinline__ float dpp_ror_add(float v) {
  const int m = __builtin_amdgcn_update_dpp(
      0, __builtin_bit_cast(int, v), CTRL, 0xf, 0xf, true);
  return v + __builtin_bit_cast(float, m);
}

__global__ __launch_bounds__(1024, 4) void fused_mlp_kernel(
    const float* __restrict__ x, const float* __restrict__ W1,
    const float* __restrict__ W2, float* __restrict__ out) {
  __shared__ __align__(16) unsigned short w1s[HIDDEN * XK];    // 43008 B, W1^T bf16
  __shared__ __align__(16) unsigned short xs[TILE_ROWS * XK];  // 86016 B, x tile bf16
  __shared__ __align__(16) float w2s[HIDDEN * 3];              // 1536 B

  const int tid = threadIdx.x;
  const int ln = tid & 15;
  const int quad = (tid >> 4) & 3;  // 16-lane group within the wave
  const int wave = tid >> 6;
  const int l = tid & 63;

  // ---- stage W1^T as bf16 into LDS ----
  for (int idx = tid; idx < IN_DIM * HIDDEN; idx += BLOCK_THREADS) {
    const int k = idx >> 7;
    const int n = idx & 127;
    w1s[n * XK + k] = f2bf(W1[idx]);
  }
  for (int idx = tid; idx < HIDDEN * 16; idx += BLOCK_THREADS) {  // zero k-pad 155..167
    const int n = idx >> 4;
    const int k = 152 + (idx & 15);
    if (k >= IN_DIM) w1s[n * XK + k] = 0;
  }
  // zero xs k-pad cols 155..167 (never overwritten by staging)
  for (int idx = tid; idx < TILE_ROWS * 13; idx += BLOCK_THREADS) {
    const int r = idx / 13;
    const int c = IN_DIM + (idx - r * 13);
    xs[r * XK + c] = 0;
  }
  // W2 into LDS (keeps VGPR count under the 4-wave/SIMD cap)
  for (int idx = tid; idx < HIDDEN * 3; idx += BLOCK_THREADS) w2s[idx] = W2[idx];
  __syncthreads();

  const size_t block_e0 = (size_t)blockIdx.x * ROWS_PER_BLOCK * IN_DIM;
  const size_t brow0 = (size_t)blockIdx.x * ROWS_PER_BLOCK;

  // epilogue routing: dst lane l (<48) pulls from src lane 16*(l/12) + (l%12)
  const int srcaddr = ((l / 12) * 16 + (l % 12)) << 2;

  // ---- prefetch tile 0 (flat coalesced float4, 16B aligned) ----
  fvec4 pre[F4_PER_THREAD];
  {
    const fvec4* src = reinterpret_cast<const fvec4*>(x + block_e0);
#pragma unroll
    for (int i = 0; i < F4_PER_THREAD; ++i) {
      const int f = tid + i * BLOCK_THREADS;
      if (f < TILE_F4) pre[i] = src[f];
    }
  }

  for (int t = 0; t < NTILES; ++t) {
    // ---- convert prefetched tile -> xs (bf16, padded rows) ----
#pragma unroll
    for (int i = 0; i < F4_PER_THREAD; ++i) {
      const int f = tid + i * BLOCK_THREADS;
      if (f < TILE_F4) {
        const int e0 = f * 4;
        const int r = e0 / IN_DIM;
        const int c = e0 - r * IN_DIM;
#pragma unroll
        for (int j = 0; j < 4; ++j) {
          const int cc = c + j;
          const int wrap = (cc >= IN_DIM);
          xs[(r + wrap) * XK + (cc - wrap * IN_DIM)] = f2bf(pre[i][j]);
        }
      }
    }
    __syncthreads();

    // ---- issue next tile's loads AFTER the barrier (barrier drains vmcnt;
    //      issued here they stay in flight under compute + epilogue) ----
    if (t + 1 < NTILES) {
      const fvec4* src = reinterpret_cast<const fvec4*>(
          x + block_e0 + (size_t)(t + 1) * TILE_ELEMS);
#pragma unroll
      for (int i = 0; i < F4_PER_THREAD; ++i) {
        const int f = tid + i * BLOCK_THREADS;
        if (f < TILE_F4) pre[i] = src[f];
      }
    }

    // ---- layer 1: 16 rows per wave, B-frags from LDS ----
    floatx4 acc[8];
#pragma unroll
    for (int c8 = 0; c8 < 8; ++c8) acc[c8] = (floatx4)0.f;
    const int rbase = wave * 16;
#pragma unroll
    for (int s = 0; s < 5; ++s) {
      const int kb = s * 32 + quad * 8;
      const short8 a = *reinterpret_cast<const short8*>(&xs[(rbase + ln) * XK + kb]);
#pragma unroll
      for (int t8 = 0; t8 < 8; ++t8) {
        const short8 b = *reinterpret_cast<const short8*>(&w1s[(t8 * 16 + ln) * XK + kb]);
        acc[t8] = __builtin_amdgcn_mfma_f32_16x16x32_bf16(a, b, acc[t8], 0, 0, 0);
      }
    }

    // ---- layer 2: relu + W2, reduce across 16-lane group ----
    // acc[t8][r] = h[row0 + quad*4 + r][16*t8 + ln]
    float part[4][3];
#pragma unroll
    for (int r = 0; r < 4; ++r)
#pragma unroll
      for (int c = 0; c < 3; ++c) part[r][c] = 0.f;
#pragma unroll
    for (int t8 = 0; t8 < 8; ++t8) {
      const float wa = w2s[(t8 * 16 + ln) * 3 + 0];
      const float wb = w2s[(t8 * 16 + ln) * 3 + 1];
      const float wc = w2s[(t8 * 16 + ln) * 3 + 2];
#pragma unroll
      for (int r = 0; r < 4; ++r) {
        const float hv = fmaxf(acc[t8][r], 0.f);
        part[r][0] = fmaf(hv, wa, part[r][0]);
        part[r][1] = fmaf(hv, wb, part[r][1]);
        part[r][2] = fmaf(hv, wc, part[r][2]);
      }
    }
    // full 16-lane reduce on DPP row_ror (VALU pipe; no DS ops, no conflicts)
#pragma unroll
    for (int r = 0; r < 4; ++r)
#pragma unroll
      for (int c = 0; c < 3; ++c) {
        float v = part[r][c];
        v = dpp_ror_add<0x128>(v);  // ror 8
        v = dpp_ror_add<0x124>(v);  // ror 4
        v = dpp_ror_add<0x122>(v);  // ror 2
        v = dpp_ror_add<0x121>(v);  // ror 1
        part[r][c] = v;
      }

    // ---- single coalesced 192B store per wave ----
    // lane j (j<12) of each 16-lane group selects part[j/3][j%3] (cndmask
    // tree), then dst lane l pulls from lane 16*(l/12) + (l%12).
    float v = part[0][0];
    v = (ln == 1) ? part[0][1] : v;
    v = (ln == 2) ? part[0][2] : v;
    v = (ln == 3) ? part[1][0] : v;
    v = (ln == 4) ? part[1][1] : v;
    v = (ln == 5) ? part[1][2] : v;
    v = (ln == 6) ? part[2][0] : v;
    v = (ln == 7) ? part[2][1] : v;
    v = (ln == 8) ? part[2][2] : v;
    v = (ln == 9) ? part[3][0] : v;
    v = (ln == 10) ? part[3][1] : v;
    v = (ln == 11) ? part[3][2] : v;
    const int vo = __builtin_amdgcn_ds_bpermute(srcaddr, __builtin_bit_cast(int, v));
    const size_t row0 = brow0 + (size_t)t * TILE_ROWS + wave * 16;
    if (l < 48) out[row0 * 3 + l] = __builtin_bit_cast(float, vo);

    __syncthreads();  // all waves done reading xs before next overwrite
  }
}

extern "C" void kernel_launch(void* const* d_in, const int* in_sizes, int n_in,
                              void* d_out, int out_size, void* d_ws, size_t ws_size,
                              hipStream_t stream) {
  const float* x = (const float*)d_in[0];
  const float* W1 = (const float*)d_in[1];
  const float* W2 = (const float*)d_in[2];
  float* out = (float*)d_out;
  fused_mlp_kernel<<<dim3(N_TOTAL / ROWS_PER_BLOCK), dim3(BLOCK_THREADS), 0, stream>>>(
      x, W1, W2, out);
}